// Round 5
// baseline (118.848 us; speedup 1.0000x reference)
//
#include <hip/hip_runtime.h>
#include <hip/hip_bf16.h>

// MultiHeadAttentionNoBatch: T=2048, D_IN=1024, D_OUT=1024, H=16, Dh=64, fp32 in/out.
// split(x,W)->bf16 hi/lo; qkv_proj: Q/K 3-term bf16 split GEMM (2-deep gload_lds
// pipeline, 64KB LDS, 2 blocks/CU), V single-term. Flash attention: 32x32x16 MFMA,
// 32 q-rows/wave (swapped S^T = K Q^T so softmax is lane-local; in-register P
// redistribution via one lane^32 shuffle), 2-wave blocks, dbuf K/V, 1 barrier/tile.
// NOTE: reference multiplies scores by sqrt(Dh)=8 -> folded into exp2 scale.

typedef __bf16 bf16x8 __attribute__((ext_vector_type(8)));
typedef __bf16 bf16x4 __attribute__((ext_vector_type(4)));
typedef float  f32x4  __attribute__((ext_vector_type(4)));
typedef float  f32x16 __attribute__((ext_vector_type(16)));
typedef unsigned int u32;
typedef u32 u32x2 __attribute__((ext_vector_type(2)));
typedef u32 u32x4 __attribute__((ext_vector_type(4)));

#define MFMA(a, b, c) __builtin_amdgcn_mfma_f32_16x16x32_bf16((a), (b), (c), 0, 0, 0)
#define MFMA32(a, b, c) __builtin_amdgcn_mfma_f32_32x32x16_bf16((a), (b), (c), 0, 0, 0)

#if __has_builtin(__builtin_amdgcn_exp2f)
#define EXP2F(x) __builtin_amdgcn_exp2f(x)
#else
#define EXP2F(x) exp2f(x)
#endif

constexpr int T = 2048, DIN = 1024, DOUT = 1024, NH = 16, DH = 64;
constexpr float SC = 11.5415603f;   // 8 * log2(e): scores scaled by sqrt(Dh)=8
constexpr float DEFER = 0.6931472f; // 8 exponent-bits / SC: defer-max threshold

// workspace layout (bytes); total 40 MiB
constexpr size_t SZ_XMAT = (size_t)T * DIN * 2;     // 4 MiB
constexpr size_t SZ_WMAT = (size_t)DOUT * DIN * 2;  // 2 MiB
constexpr size_t OFF_XH = 0;
constexpr size_t OFF_XL = OFF_XH + SZ_XMAT;
constexpr size_t OFF_QH = OFF_XL + SZ_XMAT;
constexpr size_t OFF_QL = OFF_QH + SZ_XMAT;
constexpr size_t OFF_KH = OFF_QL + SZ_XMAT;
constexpr size_t OFF_KL = OFF_KH + SZ_XMAT;
constexpr size_t OFF_VT = OFF_KL + SZ_XMAT;         // V^T bf16 [1024][2048]
constexpr size_t OFF_W  = OFF_VT + SZ_XMAT;         // 3 x (W_hi, W_lo)

__device__ __forceinline__ void gload_lds16(const void* g, void* l) {
  __builtin_amdgcn_global_load_lds(
      (const __attribute__((address_space(1))) void*)g,
      (__attribute__((address_space(3))) void*)l, 16, 0, 0);
}

// ---------------- split fp32 -> bf16 hi + bf16 lo (x and 3 W in one launch) ----
__global__ void split_all(const float* __restrict__ x, const float* __restrict__ wq,
                          const float* __restrict__ wk, const float* __restrict__ wv,
                          char* __restrict__ ws) {
  const int i = blockIdx.x * 256 + threadIdx.x;
  const float* src;
  __bf16 *hi, *lo;
  int off;
  if (i < T * DIN / 4) {  // 524288 f32x4 groups of x
    src = x; off = i;
    hi = (__bf16*)(ws + OFF_XH);
    lo = (__bf16*)(ws + OFF_XL);
  } else {
    const int j = i - T * DIN / 4;
    const int z = j >> 18;          // DOUT*DIN/4 = 262144 = 2^18
    off = j & 262143;
    src = (z == 0) ? wq : ((z == 1) ? wk : wv);
    hi = (__bf16*)(ws + OFF_W + (size_t)z * 2 * SZ_WMAT);
    lo = hi + (size_t)DOUT * DIN;
  }
  const f32x4 v = ((const f32x4*)src)[off];
  bf16x4 h, l;
#pragma unroll
  for (int j = 0; j < 4; ++j) {
    const float xv = v[j];
    const __bf16 hh = (__bf16)xv;
    h[j] = hh;
    l[j] = (__bf16)(xv - (float)hh);
  }
  ((bf16x4*)hi)[off] = h;
  ((bf16x4*)lo)[off] = l;
}

// ---------------- QKV projection main loop (unchanged from r4: ~LDS-port-bound) --
template <bool SPLIT>
__device__ __forceinline__ void proj_loop(const __bf16* __restrict__ Ah,
                                          const __bf16* __restrict__ Al,
                                          const __bf16* __restrict__ Bh,
                                          const __bf16* __restrict__ Bl,
                                          __bf16* lds, int tm, int tn, int lane,
                                          int wv, f32x4 (&acc)[4][4]) {
  constexpr int BUF = SPLIT ? 16384 : 8192;   // elems per buffer
  constexpr int BOFF = SPLIT ? 8192 : 4096;   // B-array offset within buffer
  const int wm = wv >> 1, wn = wv & 1;
  const int q4 = lane >> 4, r16 = lane & 15;

  auto STAGE = [&](int ks, int buf) {
    const int k0 = ks * 32;
    __bf16* base = lds + buf * BUF;
#pragma unroll
    for (int j = 0; j < 2; ++j) {
      const int cbase = wv * 128 + j * 64;  // wave-uniform chunk base
      const int cidx = cbase + lane;        // chunk = kc*128 + row
      const int row = cidx & 127, kc = cidx >> 7;
      const size_t ga = (size_t)(tm + row) * DIN + k0 + kc * 8;
      const size_t gb = (size_t)(tn + row) * DIN + k0 + kc * 8;
      gload_lds16(Ah + ga, base + cbase * 8);
      gload_lds16(Bh + gb, base + BOFF + cbase * 8);
      if constexpr (SPLIT) {
        gload_lds16(Al + ga, base + 4096 + cbase * 8);
        gload_lds16(Bl + gb, base + 12288 + cbase * 8);
      }
    }
  };

  STAGE(0, 0);
  STAGE(1, 1);

  for (int ks = 0; ks < 32; ++ks) {
    const int buf = ks & 1;
    if (ks < 31) {
      if constexpr (SPLIT) asm volatile("s_waitcnt vmcnt(8)" ::: "memory");
      else                 asm volatile("s_waitcnt vmcnt(4)" ::: "memory");
    } else {
      asm volatile("s_waitcnt vmcnt(0)" ::: "memory");
    }
    __builtin_amdgcn_s_barrier();
    __builtin_amdgcn_sched_barrier(0);

    const __bf16* ldsA = lds + buf * BUF;
    const __bf16* ldsB = ldsA + BOFF;

    bf16x8 fah[4], fbh[4], fal[4], fbl[4];
#pragma unroll
    for (int b = 0; b < 4; ++b) {
      const int ra = wm * 64 + b * 16 + r16;
      const int rb = wn * 64 + b * 16 + r16;
      fah[b] = *(const bf16x8*)(ldsA + (q4 * 128 + ra) * 8);
      fbh[b] = *(const bf16x8*)(ldsB + (q4 * 128 + rb) * 8);
      if constexpr (SPLIT) {
        fal[b] = *(const bf16x8*)(ldsA + 4096 + (q4 * 128 + ra) * 8);
        fbl[b] = *(const bf16x8*)(ldsB + 4096 + (q4 * 128 + rb) * 8);
      }
    }
    __builtin_amdgcn_s_setprio(1);
#pragma unroll
    for (int bm = 0; bm < 4; ++bm)
#pragma unroll
      for (int bn = 0; bn < 4; ++bn) {
        acc[bm][bn] = MFMA(fah[bm], fbh[bn], acc[bm][bn]);
        if constexpr (SPLIT) {
          acc[bm][bn] = MFMA(fah[bm], fbl[bn], acc[bm][bn]);
          acc[bm][bn] = MFMA(fal[bm], fbh[bn], acc[bm][bn]);
        }
      }
    __builtin_amdgcn_s_setprio(0);
    asm volatile("s_waitcnt lgkmcnt(0)" ::: "memory");
    __builtin_amdgcn_sched_barrier(0);
    __builtin_amdgcn_s_barrier();
    __builtin_amdgcn_sched_barrier(0);
    if (ks < 30) STAGE(ks + 2, buf);
  }
}

__global__ __launch_bounds__(256, 2) void qkv_proj(char* ws) {
  const int bid = blockIdx.x;
  const int z = bid >> 7;
  const int t_ = bid & 127;
  const int tm = (t_ >> 3) * 128;
  const int tn = (t_ & 7) * 128;
  const int tid = threadIdx.x;
  const int lane = tid & 63, wv = tid >> 6;
  const int wm = wv >> 1, wn = wv & 1;
  const int q4 = lane >> 4, r16 = lane & 15;

  const __bf16* Ah = (const __bf16*)(ws + OFF_XH);
  const __bf16* Al = (const __bf16*)(ws + OFF_XL);
  const __bf16* Bh = (const __bf16*)(ws + OFF_W + (size_t)z * 2 * SZ_WMAT);
  const __bf16* Bl = Bh + (size_t)DOUT * DIN;

  __shared__ alignas(16) __bf16 lds[32768];  // 64 KB

  f32x4 acc[4][4] = {};

  if (z < 2) {
    proj_loop<true>(Ah, Al, Bh, Bl, lds, tm, tn, lane, wv, acc);
    __bf16* Oh = (__bf16*)(ws + (z == 0 ? OFF_QH : OFF_KH));
    __bf16* Ol = (__bf16*)(ws + (z == 0 ? OFF_QL : OFF_KL));
#pragma unroll
    for (int bm = 0; bm < 4; ++bm)
#pragma unroll
      for (int bn = 0; bn < 4; ++bn)
#pragma unroll
        for (int r = 0; r < 4; ++r) {
          const int t = tm + wm * 64 + bm * 16 + q4 * 4 + r;  // D: row=(l>>4)*4+r
          const int n = tn + wn * 64 + bn * 16 + r16;         // D: col=l&15
          const float v = acc[bm][bn][r];
          const __bf16 hh = (__bf16)v;
          Oh[(size_t)t * DOUT + n] = hh;
          Ol[(size_t)t * DOUT + n] = (__bf16)(v - (float)hh);
        }
  } else {
    proj_loop<false>(Ah, Al, Bh, Bl, lds, tm, tn, lane, wv, acc);
    // V: transpose through LDS, store V^T[1024][2048]
    __syncthreads();
    __bf16* tb = lds;  // [128][136]
#pragma unroll
    for (int bm = 0; bm < 4; ++bm)
#pragma unroll
      for (int bn = 0; bn < 4; ++bn)
#pragma unroll
        for (int r = 0; r < 4; ++r) {
          const int tl = wm * 64 + bm * 16 + q4 * 4 + r;
          const int nl = wn * 64 + bn * 16 + r16;
          tb[(size_t)nl * 136 + tl] = (__bf16)acc[bm][bn][r];
        }
    __syncthreads();
    __bf16* Vt = (__bf16*)(ws + OFF_VT);
#pragma unroll
    for (int it = 0; it < 8; ++it) {
      const int cid = it * 256 + tid;
      const int nl = cid >> 4, tc = cid & 15;
      const bf16x8 vd = *(const bf16x8*)(tb + (size_t)nl * 136 + tc * 8);
      *(bf16x8*)(Vt + (size_t)(tn + nl) * T + tm + tc * 8) = vd;
    }
  }
}

// ---------------- flash attention: 32x32x16, 32 q/wave, 2-wave blocks ----------
// S^T[k,q] = mfma32(A=K, B=Q): A row = lane&31 = k-row, d = (lane>>5)*8+j;
// B col = lane&31 = q. D: col = lane&31 = q, k-row = (reg&3)+8*(reg>>2)+4*(lane>>5).
// Each lane holds 32 P-values of ONE q -> softmax: 31 fmax + 1 shfl_xor(32).
// PV B-frag P[k=ks*16+hi*8+j][q]: own quad + partner-lane quad via 1 shfl_xor(32).
__global__ __launch_bounds__(128, 2) void attn_kernel(const char* __restrict__ ws,
                                                      float* __restrict__ out) {
  const int bid = blockIdx.x;
  const int h = bid & 15;
  // pairing: blocks c and c+256 (co-resident) get qt summing to 31
  const int qt = (bid < 256) ? (31 - (bid >> 4)) : ((bid - 256) >> 4);
  const int tid = threadIdx.x;
  const int lane = tid & 63, wid = tid >> 6;  // 2 waves
  const int r32 = lane & 31, hi = lane >> 5;
  const int hi8 = hi * 8;

  const __bf16* Qh = (const __bf16*)(ws + OFF_QH);
  const __bf16* Ql = (const __bf16*)(ws + OFF_QL);
  const __bf16* Kh = (const __bf16*)(ws + OFF_KH);
  const __bf16* Kl = (const __bf16*)(ws + OFF_KL);
  const __bf16* Vt = (const __bf16*)(ws + OFF_VT);

  __shared__ alignas(16) __bf16 sKh[2][64 * 72];  // +8 pad
  __shared__ alignas(16) __bf16 sKl[2][64 * 72];
  __shared__ alignas(16) __bf16 sVt[2][64 * 72];  // [d][kv]

  const int qbase = qt * 64 + wid * 32;
  const int qg = qbase + r32;  // this lane's q row

  // Q B-frags (col=lane&31=q, d=ds*16+hi*8+j) held in registers
  bf16x8 fqh[4], fql[4];
#pragma unroll
  for (int ds = 0; ds < 4; ++ds) {
    const size_t off = (size_t)qg * DOUT + h * 64 + ds * 16 + hi8;
    fqh[ds] = *(const bf16x8*)(Qh + off);
    fql[ds] = *(const bf16x8*)(Ql + off);
  }

  // staging registers (T14): 128 threads x 12 chunks = 3 arrays x 64 rows x 64 d
  bf16x8 st[12];
  const int srow = tid >> 3, sdc = tid & 7;  // srow 0..15
  auto ISSUE = [&](int kvt) {
    const int kv0 = kvt * 64;
#pragma unroll
    for (int k = 0; k < 4; ++k) {
      const int row = srow + 16 * k;
      const size_t koff = (size_t)(kv0 + row) * DOUT + h * 64 + sdc * 8;
      st[3 * k + 0] = *(const bf16x8*)(Kh + koff);
      st[3 * k + 1] = *(const bf16x8*)(Kl + koff);
      st[3 * k + 2] = *(const bf16x8*)(Vt + (size_t)(h * 64 + row) * T + kv0 + sdc * 8);
    }
  };
  auto WRITE = [&](int b) {
#pragma unroll
    for (int k = 0; k < 4; ++k) {
      const int row = srow + 16 * k;
      *(bf16x8*)(&sKh[b][row * 72 + sdc * 8]) = st[3 * k + 0];
      *(bf16x8*)(&sKl[b][row * 72 + sdc * 8]) = st[3 * k + 1];
      *(bf16x8*)(&sVt[b][row * 72 + sdc * 8]) = st[3 * k + 2];
    }
  };

  f32x16 acc0 = {}, acc1 = {};  // O^T: d-blocks 0,1; col=q, row=d (crow)
  float mrun = -1e30f, lrun = 0.f;

  ISSUE(0);
  asm volatile("s_waitcnt vmcnt(0)" ::: "memory");
  WRITE(0);
  if (qt > 0) ISSUE(1);
  asm volatile("s_waitcnt lgkmcnt(0)" ::: "memory");
  __builtin_amdgcn_s_barrier();
  __builtin_amdgcn_sched_barrier(0);

  for (int kvt = 0; kvt <= qt; ++kvt) {
    const int cur = kvt & 1;
    const int kv0 = kvt * 64;
    const bool diag = (kvt == qt);

    // S^T = K Q^T, 3-term; wave 0 skips upper k-block on its diagonal tile
    f32x16 s0 = {}, s1 = {};
    const bool do1 = !(diag && wid == 0);
    __builtin_amdgcn_s_setprio(1);
#pragma unroll
    for (int ds = 0; ds < 4; ++ds) {
      const int ko = ds * 16 + hi8;
      const bf16x8 kh0 = *(const bf16x8*)(&sKh[cur][r32 * 72 + ko]);
      const bf16x8 kl0 = *(const bf16x8*)(&sKl[cur][r32 * 72 + ko]);
      s0 = MFMA32(kh0, fqh[ds], s0);
      s0 = MFMA32(kl0, fqh[ds], s0);
      s0 = MFMA32(kh0, fql[ds], s0);
    }
    if (do1) {
#pragma unroll
      for (int ds = 0; ds < 4; ++ds) {
        const int ko = ds * 16 + hi8;
        const bf16x8 kh1 = *(const bf16x8*)(&sKh[cur][(32 + r32) * 72 + ko]);
        const bf16x8 kl1 = *(const bf16x8*)(&sKl[cur][(32 + r32) * 72 + ko]);
        s1 = MFMA32(kh1, fqh[ds], s1);
        s1 = MFMA32(kl1, fqh[ds], s1);
        s1 = MFMA32(kh1, fql[ds], s1);
      }
    }
    __builtin_amdgcn_s_setprio(0);

    if (diag) {  // causal mask: k > q (skipped s1 stays 0 -> masked here)
#pragma unroll
      for (int r = 0; r < 16; ++r) {
        const int kr = (r & 3) + 8 * (r >> 2) + 4 * hi;
        if (kv0 + kr > qg) s0[r] = -1e30f;
        if (kv0 + 32 + kr > qg) s1[r] = -1e30f;
      }
    }

    // lane-local softmax (q = lane&31; partner lane^32 has same q)
    float mx = -1e30f;
#pragma unroll
    for (int r = 0; r < 16; ++r) {
      mx = fmaxf(mx, s0[r]);
      mx = fmaxf(mx, s1[r]);
    }
    mx = fmaxf(mx, __shfl_xor(mx, 32, 64));

    if (__any(mx - mrun > DEFER)) {  // defer-max: rescale only on real growth
      const float mnew = fmaxf(mrun, mx);
      const float scale = EXP2F((mrun - mnew) * SC);
      mrun = mnew;
      lrun *= scale;
#pragma unroll
      for (int r = 0; r < 16; ++r) {
        acc0[r] *= scale;
        acc1[r] *= scale;
      }
    }
    const float mn2 = mrun * SC;

    float ps = 0.f;
#pragma unroll
    for (int r = 0; r < 16; ++r) {
      s0[r] = EXP2F(__builtin_fmaf(s0[r], SC, -mn2));
      s1[r] = EXP2F(__builtin_fmaf(s1[r], SC, -mn2));
      ps += s0[r] + s1[r];
    }
    ps += __shfl_xor(ps, 32, 64);
    lrun += ps;

    // P -> PV B-frags: frag[ks] = P[k=ks*16+hi*8+j][q]; per ks the low quad
    // comes from the reg-low pack, high quad from reg-high pack, with one
    // lane^32 exchange (group0 lanes hold k%8<4, group1 k%8>=4).
    bf16x8 pb[4];
#pragma unroll
    for (int ks = 0; ks < 4; ++ks) {
      const int rb = (ks & 1) * 8;
      bf16x4 lo4, hi4;
#pragma unroll
      for (int j = 0; j < 4; ++j) {
        const float pl = (ks < 2) ? s0[rb + j] : s1[rb + j];
        const float ph = (ks < 2) ? s0[rb + 4 + j] : s1[rb + 4 + j];
        lo4[j] = (__bf16)pl;
        hi4[j] = (__bf16)ph;
      }
      const u32x2 L = __builtin_bit_cast(u32x2, lo4);
      const u32x2 H = __builtin_bit_cast(u32x2, hi4);
      u32x4 f;
#pragma unroll
      for (int t = 0; t < 2; ++t) {
        const u32 send = hi ? L[t] : H[t];
        const u32 recv = (u32)__shfl_xor((int)send, 32, 64);
        f[t] = hi ? recv : L[t];      // frag low quad
        f[2 + t] = hi ? H[t] : recv;  // frag high quad
      }
      pb[ks] = __builtin_bit_cast(bf16x8, f);
    }

    // O^T += V^T P : A = V^T (row=lane&31=d, kv=ks*16+hi*8+j), B = P
    __builtin_amdgcn_s_setprio(1);
#pragma unroll
    for (int ks = 0; ks < 4; ++ks) {
      const int vo = ks * 16 + hi8;
      const bf16x8 va0 = *(const bf16x8*)(&sVt[cur][r32 * 72 + vo]);
      const bf16x8 va1 = *(const bf16x8*)(&sVt[cur][(32 + r32) * 72 + vo]);
      acc0 = MFMA32(va0, pb[ks], acc0);
      acc1 = MFMA32(va1, pb[ks], acc1);
    }
    __builtin_amdgcn_s_setprio(0);

    if (kvt < qt) {  // stage tile kvt+1 into the other buffer; refill st
      asm volatile("s_waitcnt vmcnt(0)" ::: "memory");
      WRITE(cur ^ 1);
      if (kvt + 1 < qt) ISSUE(kvt + 2);
    }
    asm volatile("s_waitcnt lgkmcnt(0)" ::: "memory");
    __builtin_amdgcn_sched_barrier(0);
    __builtin_amdgcn_s_barrier();  // single barrier per tile
    __builtin_amdgcn_sched_barrier(0);
  }

  const float rl = 1.0f / lrun;
#pragma unroll
  for (int r = 0; r < 16; ++r) {
    const int d = (r & 3) + 8 * (r >> 2) + 4 * hi;
    out[(size_t)qg * DOUT + h * 64 + d] = acc0[r] * rl;
    out[(size_t)qg * DOUT + h * 64 + 32 + d] = acc1[r] * rl;
  }
}

// ---------------- launch ----------------
extern "C" void kernel_launch(void* const* d_in, const int* in_sizes, int n_in,
                              void* d_out, int out_size, void* d_ws, size_t ws_size,
                              hipStream_t stream) {
  const float* x  = (const float*)d_in[0];
  const float* Wq = (const float*)d_in[1];
  const float* Wk = (const float*)d_in[2];
  const float* Wv = (const float*)d_in[3];
  char* ws = (char*)d_ws;

  split_all<<<5120, 256, 0, stream>>>(x, Wq, Wk, Wv, ws);
  qkv_proj<<<384, 256, 0, stream>>>(ws);
  attn_kernel<<<512, 128, 0, stream>>>(ws, (float*)d_out);
}